// Round 16
// baseline (132.142 us; speedup 1.0000x reference)
//
#include <hip/hip_runtime.h>

// UniGCNConv2: bucketed counting sort (packed keys, no global atomics) ->
// X cast bf16 (fused into p1) -> gather segment-mean Xe (bf16 store, f32
// accum, 8 edges/wave) -> FUSED node pass: gather+degv+L2norm (16 nodes per
// wave, 2 per 8-lane group) + wave-local LDS strip + MFMA linear, no
// inter-wave barrier. 6 launches. N=100000, M=200000, E=1e6, D=64, out 128.

#define DIN 64
#define DOUT 128
#define CH 4096
#define BSHIFT 9          // fine range 512
#define FINE 512
#define PAYBITS 18
#define PAYMASK ((1u << PAYBITS) - 1u)
#define XB 256            // xcast helper blocks fused into p1
#define STAGE 8192        // p3 LDS pair-staging capacity
#define WPAD 72

typedef float f32x4 __attribute__((ext_vector_type(4)));
typedef short bf16x8 __attribute__((ext_vector_type(8)));

__device__ __forceinline__ unsigned short f2b(float f) {
  unsigned u = __float_as_uint(f);
  u = u + 0x7fffu + ((u >> 16) & 1u);   // RNE
  return (unsigned short)(u >> 16);
}
__device__ __forceinline__ float b2f(unsigned s) {
  return __uint_as_float(s << 16);
}

// ---- P1 (512 thr): blocks [0,NCH): coarse hist (int4 reads);
// [NCH,NCH+XB): X->bf16. Block 0 zeroes the done counter.
__global__ __launch_bounds__(512) void k_p1(
    const int* __restrict__ vertex, const int* __restrict__ edges,
    int* __restrict__ G, const float* __restrict__ X,
    unsigned short* __restrict__ Xb, int* __restrict__ done,
    int E, int BKE, int BK, int NCH, int total4) {
  if (blockIdx.x == 0 && threadIdx.x == 0) *done = 0;
  if (blockIdx.x >= (unsigned)NCH) {  // xcast role
    int xb = blockIdx.x - NCH;
    for (int i = xb * 512 + threadIdx.x; i < total4; i += XB * 512) {
      float4 a = ((const float4*)X)[i];
      ushort4 r;
      r.x = f2b(a.x); r.y = f2b(a.y); r.z = f2b(a.z); r.w = f2b(a.w);
      ((ushort4*)Xb)[i] = r;
    }
    return;
  }
  __shared__ int h[1024];
  for (int i = threadIdx.x; i < BK; i += 512) h[i] = 0;
  __syncthreads();
  int c = blockIdx.x;
  int s = c * CH, e_ = min(E, s + CH);
  int n4 = (e_ - s) >> 2;
  const int4* ep = (const int4*)(edges + s);
  const int4* vp = (const int4*)(vertex + s);
  for (int i = threadIdx.x; i < n4; i += 512) {
    int4 ee = ep[i], vv = vp[i];
    atomicAdd(&h[ee.x >> BSHIFT], 1); atomicAdd(&h[ee.y >> BSHIFT], 1);
    atomicAdd(&h[ee.z >> BSHIFT], 1); atomicAdd(&h[ee.w >> BSHIFT], 1);
    atomicAdd(&h[BKE + (vv.x >> BSHIFT)], 1); atomicAdd(&h[BKE + (vv.y >> BSHIFT)], 1);
    atomicAdd(&h[BKE + (vv.z >> BSHIFT)], 1); atomicAdd(&h[BKE + (vv.w >> BSHIFT)], 1);
  }
  for (int i = s + (n4 << 2) + threadIdx.x; i < e_; i += 512) {
    atomicAdd(&h[edges[i] >> BSHIFT], 1);
    atomicAdd(&h[BKE + (vertex[i] >> BSHIFT)], 1);
  }
  __syncthreads();
  for (int b = threadIdx.x; b < BK; b += 512) G[(size_t)b * NCH + c] = h[b];
}

// ---- P1b: per-bucket row scan across chunks; last block scans bucket totals.
__global__ __launch_bounds__(256) void k_p1b(
    int* __restrict__ G, int* __restrict__ rowTot, int* __restrict__ bucketBase,
    int* __restrict__ done, int NCH, int BK) {
  int b = blockIdx.x;
  int* row = G + (size_t)b * NCH;
  __shared__ int wsum[4];
  __shared__ int carry;
  __shared__ bool amLast;
  if (threadIdx.x == 0) carry = 0;
  __syncthreads();
  for (int base = 0; base < NCH; base += 256) {
    int i = base + threadIdx.x;
    int v = (i < NCH) ? row[i] : 0;
    int lane = threadIdx.x & 63, wid = threadIdx.x >> 6;
    int inc = v;
    #pragma unroll
    for (int o = 1; o < 64; o <<= 1) {
      int t = __shfl_up(inc, o);
      if (lane >= o) inc += t;
    }
    if (lane == 63) wsum[wid] = inc;
    __syncthreads();
    int woff = carry;
    for (int w = 0; w < wid; ++w) woff += wsum[w];
    int excl = woff + inc - v;
    if (i < NCH) row[i] = excl;
    __syncthreads();
    if (threadIdx.x == 0) carry += wsum[0] + wsum[1] + wsum[2] + wsum[3];
    __syncthreads();
  }
  if (threadIdx.x == 0) {
    rowTot[b] = carry;
    __threadfence();
    amLast = (atomicAdd(done, 1) == gridDim.x - 1);
  }
  __syncthreads();
  if (!amLast) return;

  if (threadIdx.x == 0) carry = 0;
  __syncthreads();
  for (int base = 0; base < BK; base += 256) {
    int i = base + threadIdx.x;
    int v = (i < BK) ? atomicAdd(&rowTot[i], 0) : 0;  // device-fresh read
    int lane = threadIdx.x & 63, wid = threadIdx.x >> 6;
    int inc = v;
    #pragma unroll
    for (int o = 1; o < 64; o <<= 1) {
      int t = __shfl_up(inc, o);
      if (lane >= o) inc += t;
    }
    if (lane == 63) wsum[wid] = inc;
    __syncthreads();
    int woff = carry;
    for (int w = 0; w < wid; ++w) woff += wsum[w];
    int excl = woff + inc - v;
    if (i < BK) bucketBase[i] = excl;
    __syncthreads();
    if (threadIdx.x == 0) carry += wsum[0] + wsum[1] + wsum[2] + wsum[3];
    __syncthreads();
  }
  if (threadIdx.x == 0) bucketBase[BK] = carry;
}

// ---- P2 (512 thr): scatter packed (fine,payload) via LDS cursors; int4 reads.
__global__ __launch_bounds__(512) void p2_scatter(
    const int* __restrict__ vertex, const int* __restrict__ edges,
    const int* __restrict__ G, const int* __restrict__ bucketBase,
    unsigned* __restrict__ temp, int E, int BKE, int BK, int NCH) {
  __shared__ int curs[1024];
  int c = blockIdx.x;
  for (int b = threadIdx.x; b < BK; b += 512)
    curs[b] = bucketBase[b] + G[(size_t)b * NCH + c];
  __syncthreads();
  int s = c * CH, e_ = min(E, s + CH);
  int n4 = (e_ - s) >> 2;
  const int4* ep = (const int4*)(edges + s);
  const int4* vp = (const int4*)(vertex + s);
  for (int i = threadIdx.x; i < n4; i += 512) {
    int4 ee = ep[i], vv = vp[i];
    int p;
    p = atomicAdd(&curs[ee.x >> BSHIFT], 1);
    temp[p] = ((unsigned)(ee.x & (FINE - 1)) << PAYBITS) | (unsigned)vv.x;
    p = atomicAdd(&curs[BKE + (vv.x >> BSHIFT)], 1);
    temp[p] = ((unsigned)(vv.x & (FINE - 1)) << PAYBITS) | (unsigned)ee.x;
    p = atomicAdd(&curs[ee.y >> BSHIFT], 1);
    temp[p] = ((unsigned)(ee.y & (FINE - 1)) << PAYBITS) | (unsigned)vv.y;
    p = atomicAdd(&curs[BKE + (vv.y >> BSHIFT)], 1);
    temp[p] = ((unsigned)(vv.y & (FINE - 1)) << PAYBITS) | (unsigned)ee.y;
    p = atomicAdd(&curs[ee.z >> BSHIFT], 1);
    temp[p] = ((unsigned)(ee.z & (FINE - 1)) << PAYBITS) | (unsigned)vv.z;
    p = atomicAdd(&curs[BKE + (vv.z >> BSHIFT)], 1);
    temp[p] = ((unsigned)(vv.z & (FINE - 1)) << PAYBITS) | (unsigned)ee.z;
    p = atomicAdd(&curs[ee.w >> BSHIFT], 1);
    temp[p] = ((unsigned)(ee.w & (FINE - 1)) << PAYBITS) | (unsigned)vv.w;
    p = atomicAdd(&curs[BKE + (vv.w >> BSHIFT)], 1);
    temp[p] = ((unsigned)(vv.w & (FINE - 1)) << PAYBITS) | (unsigned)ee.w;
  }
  for (int i = s + (n4 << 2) + threadIdx.x; i < e_; i += 512) {
    int e = edges[i], v = vertex[i];
    int pE = atomicAdd(&curs[e >> BSHIFT], 1);
    temp[pE] = ((unsigned)(e & (FINE - 1)) << PAYBITS) | (unsigned)v;
    int pV = atomicAdd(&curs[BKE + (v >> BSHIFT)], 1);
    temp[pV] = ((unsigned)(v & (FINE - 1)) << PAYBITS) | (unsigned)e;
  }
}

// ---- P3: per-bucket fine counting sort -> off (inclusive ends) + perm.
__global__ __launch_bounds__(256) void p3_sort(
    const unsigned* __restrict__ temp, const int* __restrict__ bucketBase,
    int* __restrict__ off, int* __restrict__ perm, int BKE, int M, int N) {
  __shared__ int hist[FINE];
  __shared__ int pos[FINE];
  __shared__ int wsum[4];
  __shared__ unsigned pairsS[STAGE];
  int g = blockIdx.x;
  bool isE = g < BKE;
  int gg = isE ? g : g - BKE;
  int keyBase = gg << BSHIFT;
  int cap = isE ? M : N;
  int offBase = (isE ? 0 : M) + keyBase;
  int fineCount = min(FINE, cap - keyBase);
  int pairBase = bucketBase[g], pairEnd = bucketBase[g + 1];
  int cnt = pairEnd - pairBase;
  bool staged = cnt <= STAGE;

  for (int i = threadIdx.x; i < FINE; i += 256) hist[i] = 0;
  __syncthreads();
  if (staged) {
    for (int i = threadIdx.x; i < cnt; i += 256) {
      unsigned p = temp[pairBase + i];
      pairsS[i] = p;
      atomicAdd(&hist[p >> PAYBITS], 1);
    }
  } else {
    for (int i = threadIdx.x; i < cnt; i += 256)
      atomicAdd(&hist[temp[pairBase + i] >> PAYBITS], 1);
  }
  __syncthreads();

  int t2 = threadIdx.x * 2;
  int a0 = hist[t2], a1 = hist[t2 + 1];
  int tsum = a0 + a1;
  int lane = threadIdx.x & 63, wid = threadIdx.x >> 6;
  int inc = tsum;
  #pragma unroll
  for (int o = 1; o < 64; o <<= 1) {
    int t = __shfl_up(inc, o);
    if (lane >= o) inc += t;
  }
  if (lane == 63) wsum[wid] = inc;
  __syncthreads();
  int woff = 0;
  for (int w = 0; w < wid; ++w) woff += wsum[w];
  int excl = woff + inc - tsum;
  pos[t2] = excl; pos[t2 + 1] = excl + a0;
  __syncthreads();

  for (int f = threadIdx.x; f < fineCount; f += 256)
    off[offBase + f] = pairBase + pos[f] + hist[f];
  for (int f = threadIdx.x; f < FINE; f += 256) pos[f] += pairBase;
  __syncthreads();

  if (staged) {
    for (int i = threadIdx.x; i < cnt; i += 256) {
      unsigned p = pairsS[i];
      int q = atomicAdd(&pos[p >> PAYBITS], 1);
      perm[q] = (int)(p & PAYMASK);
    }
  } else {
    for (int i = threadIdx.x; i < cnt; i += 256) {
      unsigned p = temp[pairBase + i];
      int q = atomicAdd(&pos[p >> PAYBITS], 1);
      perm[q] = (int)(p & PAYMASK);
    }
  }
}

// ---- compute passes ----

// 8 hyperedges per wave, one per 8-lane group; 8 lanes × uint4 = 128B row.
__global__ __launch_bounds__(256) void k_edge(
    const unsigned short* __restrict__ Xb, const int* __restrict__ off,
    const int* __restrict__ perm, const float* __restrict__ dege,
    unsigned short* __restrict__ Xe, int M) {
  long long gid = (long long)blockIdx.x * 256 + threadIdx.x;
  int wv = (int)(gid >> 6);
  int lane = threadIdx.x & 63;
  int g = lane >> 3, li = lane & 7;     // 8 groups of 8 lanes
  int e = wv * 8 + g;
  bool valid = e < M;
  int start = 0, end = 0;
  if (valid) { start = e ? off[e - 1] : 0; end = off[e]; }
  int deg = end - start;
  int myidx = (valid && li < deg) ? perm[start + li] : 0;
  int jmax = min(deg, 8);
  int jw = jmax;
  jw = max(jw, __shfl_xor(jw, 8));
  jw = max(jw, __shfl_xor(jw, 16));
  jw = max(jw, __shfl_xor(jw, 32));
  const uint4* X4 = (const uint4*)Xb;   // 8 uint4 per 64-elem row
  float acc[8] = {0.f, 0.f, 0.f, 0.f, 0.f, 0.f, 0.f, 0.f};
  #pragma unroll 4
  for (int j = 0; j < jw; ++j) {
    int v0 = __shfl(myidx, (g << 3) + j);   // all 64 lanes active
    if (j < jmax) {
      uint4 a = X4[(size_t)v0 * 8 + li];
      acc[0] += b2f(a.x & 0xffffu); acc[1] += b2f(a.x >> 16);
      acc[2] += b2f(a.y & 0xffffu); acc[3] += b2f(a.y >> 16);
      acc[4] += b2f(a.z & 0xffffu); acc[5] += b2f(a.z >> 16);
      acc[6] += b2f(a.w & 0xffffu); acc[7] += b2f(a.w >> 16);
    }
  }
  for (int j = 8; j < deg; ++j) {           // tail (deg>8)
    int v0 = perm[start + j];
    uint4 a = X4[(size_t)v0 * 8 + li];
    acc[0] += b2f(a.x & 0xffffu); acc[1] += b2f(a.x >> 16);
    acc[2] += b2f(a.y & 0xffffu); acc[3] += b2f(a.y >> 16);
    acc[4] += b2f(a.z & 0xffffu); acc[5] += b2f(a.z >> 16);
    acc[6] += b2f(a.w & 0xffffu); acc[7] += b2f(a.w >> 16);
  }
  if (valid) {
    float s = dege[e] / fmaxf((float)deg, 1.0f);
    uint4 r;
    r.x = (unsigned)f2b(acc[0] * s) | ((unsigned)f2b(acc[1] * s) << 16);
    r.y = (unsigned)f2b(acc[2] * s) | ((unsigned)f2b(acc[3] * s) << 16);
    r.z = (unsigned)f2b(acc[4] * s) | ((unsigned)f2b(acc[5] * s) << 16);
    r.w = (unsigned)f2b(acc[6] * s) | ((unsigned)f2b(acc[7] * s) << 16);
    ((uint4*)Xe)[(size_t)e * 8 + li] = r;
  }
}

// Fused node pass: each WAVE owns a 16-node MFMA strip. 8-lane group g owns
// nodes (strip,g) and (strip,8+g): dual-stream gather (uint4, index-prefetch),
// degv scale, group-local L2 norm, bf16 rows into this wave's private LDS
// strip (no inter-wave barrier), then 16x16x32 MFMA x 16 and f32 out stores.
__global__ __launch_bounds__(256) void k_nodefin(
    const unsigned short* __restrict__ Xe, const int* __restrict__ off,
    const int* __restrict__ perm, const float* __restrict__ degv,
    const float* __restrict__ W, const float* __restrict__ bias,
    float* __restrict__ out, int N, int M) {
  __shared__ unsigned short Wt[DOUT * WPAD];                    // 18.4 KB
  __shared__ __align__(16) unsigned short xnS[4][16][WPAD];     // 9.2 KB
  for (int i = threadIdx.x; i < DIN * DOUT; i += 256) {
    int k = i >> 7, c = i & 127;   // W[k][c]
    Wt[c * WPAD + k] = f2b(W[i]);
  }
  __syncthreads();   // only barrier: Wt visible to all waves

  int wv = threadIdx.x >> 6;
  int lane = threadIdx.x & 63;
  int g = lane >> 3, li = lane & 7;
  int row0 = (blockIdx.x * 4 + wv) * 16;   // wave's strip base row
  int nA = row0 + g;
  int nB = row0 + 8 + g;
  bool vA = nA < N, vB = nB < N;
  int sA = 0, eA = 0, sB = 0, eB = 0;
  if (vA) { sA = off[M + nA - 1]; eA = off[M + nA]; }  // node0: off[M-1]==E
  if (vB) { sB = off[M + nB - 1]; eB = off[M + nB]; }
  int dA = eA - sA, dB = eB - sB;
  int myA0 = (vA && li < dA) ? perm[sA + li] : 0;
  int myA1 = (vA && 8 + li < dA) ? perm[sA + 8 + li] : 0;
  int myB0 = (vB && li < dB) ? perm[sB + li] : 0;
  int myB1 = (vB && 8 + li < dB) ? perm[sB + 8 + li] : 0;
  int jA = min(dA, 16), jB = min(dB, 16);
  int jw = max(jA, jB);
  jw = max(jw, __shfl_xor(jw, 8));
  jw = max(jw, __shfl_xor(jw, 16));
  jw = max(jw, __shfl_xor(jw, 32));
  const uint4* Xe4 = (const uint4*)Xe;
  float accA[8] = {0.f, 0.f, 0.f, 0.f, 0.f, 0.f, 0.f, 0.f};
  float accB[8] = {0.f, 0.f, 0.f, 0.f, 0.f, 0.f, 0.f, 0.f};
  #pragma unroll 2
  for (int j = 0; j < jw; ++j) {           // j wave-uniform
    int iA = (j < 8) ? __shfl(myA0, (g << 3) + j) : __shfl(myA1, (g << 3) + j - 8);
    int iB = (j < 8) ? __shfl(myB0, (g << 3) + j) : __shfl(myB1, (g << 3) + j - 8);
    if (j < jA) {
      uint4 a = Xe4[(size_t)iA * 8 + li];
      accA[0] += b2f(a.x & 0xffffu); accA[1] += b2f(a.x >> 16);
      accA[2] += b2f(a.y & 0xffffu); accA[3] += b2f(a.y >> 16);
      accA[4] += b2f(a.z & 0xffffu); accA[5] += b2f(a.z >> 16);
      accA[6] += b2f(a.w & 0xffffu); accA[7] += b2f(a.w >> 16);
    }
    if (j < jB) {
      uint4 a = Xe4[(size_t)iB * 8 + li];
      accB[0] += b2f(a.x & 0xffffu); accB[1] += b2f(a.x >> 16);
      accB[2] += b2f(a.y & 0xffffu); accB[3] += b2f(a.y >> 16);
      accB[4] += b2f(a.z & 0xffffu); accB[5] += b2f(a.z >> 16);
      accB[6] += b2f(a.w & 0xffffu); accB[7] += b2f(a.w >> 16);
    }
  }
  for (int j = 16; j < dA; ++j) {          // rare tail
    int e0 = perm[sA + j];
    uint4 a = Xe4[(size_t)e0 * 8 + li];
    accA[0] += b2f(a.x & 0xffffu); accA[1] += b2f(a.x >> 16);
    accA[2] += b2f(a.y & 0xffffu); accA[3] += b2f(a.y >> 16);
    accA[4] += b2f(a.z & 0xffffu); accA[5] += b2f(a.z >> 16);
    accA[6] += b2f(a.w & 0xffffu); accA[7] += b2f(a.w >> 16);
  }
  for (int j = 16; j < dB; ++j) {
    int e0 = perm[sB + j];
    uint4 a = Xe4[(size_t)e0 * 8 + li];
    accB[0] += b2f(a.x & 0xffffu); accB[1] += b2f(a.x >> 16);
    accB[2] += b2f(a.y & 0xffffu); accB[3] += b2f(a.y >> 16);
    accB[4] += b2f(a.z & 0xffffu); accB[5] += b2f(a.z >> 16);
    accB[6] += b2f(a.w & 0xffffu); accB[7] += b2f(a.w >> 16);
  }
  float dvA = vA ? degv[nA] : 0.f;
  float dvB = vB ? degv[nB] : 0.f;
  float ssA = 0.f, ssB = 0.f;
  #pragma unroll
  for (int i = 0; i < 8; ++i) {
    accA[i] *= dvA; ssA += accA[i] * accA[i];
    accB[i] *= dvB; ssB += accB[i] * accB[i];
  }
  #pragma unroll
  for (int o = 1; o <= 4; o <<= 1) {
    ssA += __shfl_xor(ssA, o);
    ssB += __shfl_xor(ssB, o);
  }
  float scA = ssA > 0.0f ? 1.0f / sqrtf(ssA) : 0.0f;
  float scB = ssB > 0.0f ? 1.0f / sqrtf(ssB) : 0.0f;
  // invalid nodes have acc==0 -> rows of zeros (safe for MFMA)
  uint4 rA, rB;
  rA.x = (unsigned)f2b(accA[0] * scA) | ((unsigned)f2b(accA[1] * scA) << 16);
  rA.y = (unsigned)f2b(accA[2] * scA) | ((unsigned)f2b(accA[3] * scA) << 16);
  rA.z = (unsigned)f2b(accA[4] * scA) | ((unsigned)f2b(accA[5] * scA) << 16);
  rA.w = (unsigned)f2b(accA[6] * scA) | ((unsigned)f2b(accA[7] * scA) << 16);
  rB.x = (unsigned)f2b(accB[0] * scB) | ((unsigned)f2b(accB[1] * scB) << 16);
  rB.y = (unsigned)f2b(accB[2] * scB) | ((unsigned)f2b(accB[3] * scB) << 16);
  rB.z = (unsigned)f2b(accB[4] * scB) | ((unsigned)f2b(accB[5] * scB) << 16);
  rB.w = (unsigned)f2b(accB[6] * scB) | ((unsigned)f2b(accB[7] * scB) << 16);
  *(uint4*)&xnS[wv][g][li * 8] = rA;
  *(uint4*)&xnS[wv][8 + g][li * 8] = rB;
  // no __syncthreads: this wave alone wrote/reads xnS[wv]; compiler emits
  // the lgkmcnt wait for the same-wave LDS dependency.

  // MFMA phase: A frag row = lane&15, k = (lane>>4)*8 + j [m89-verified C/D].
  int r = lane & 15, h = lane >> 4;
  bf16x8 a0 = *(const bf16x8*)&xnS[wv][r][h * 8];
  bf16x8 a1 = *(const bf16x8*)&xnS[wv][r][32 + h * 8];
  #pragma unroll
  for (int c = 0; c < 8; ++c) {
    const unsigned short* wcol = &Wt[(c * 16 + r) * WPAD];
    bf16x8 b0 = *(const bf16x8*)&wcol[h * 8];
    bf16x8 b1 = *(const bf16x8*)&wcol[32 + h * 8];
    float bc = bias[c * 16 + r];
    f32x4 o4 = {bc, bc, bc, bc};
    o4 = __builtin_amdgcn_mfma_f32_16x16x32_bf16(a0, b0, o4, 0, 0, 0);
    o4 = __builtin_amdgcn_mfma_f32_16x16x32_bf16(a1, b1, o4, 0, 0, 0);
    #pragma unroll
    for (int q = 0; q < 4; ++q) {
      int row = row0 + h * 4 + q;
      if (row < N) out[(size_t)row * DOUT + c * 16 + r] = o4[q];
    }
  }
}

extern "C" void kernel_launch(void* const* d_in, const int* in_sizes, int n_in,
                              void* d_out, int out_size, void* d_ws, size_t ws_size,
                              hipStream_t stream) {
  const float* X      = (const float*)d_in[0];
  const int*   vertex = (const int*)d_in[1];
  const int*   edges  = (const int*)d_in[2];
  const float* dege   = (const float*)d_in[3];
  const float* degv   = (const float*)d_in[4];
  const float* W      = (const float*)d_in[5];
  const float* b      = (const float*)d_in[6];
  float* out = (float*)d_out;

  int N = in_sizes[0] / DIN;   // 100000
  int E = in_sizes[1];         // 1000000
  int M = in_sizes[3];         // 200000

  int NCH = (E + CH - 1) / CH;                 // 245
  int BKE = (M + FINE - 1) >> BSHIFT;          // 391
  int BKV = (N + FINE - 1) >> BSHIFT;          // 196
  int BK  = BKE + BKV;                         // 587

  // workspace layout
  unsigned short* Xe = (unsigned short*)d_ws;               // M*64 bf16 (25.6 MB)
  unsigned short* Xb = Xe + (size_t)M * DIN;                // N*64 bf16 (12.8 MB)
  int*   off  = (int*)(Xb + (size_t)N * DIN);               // M+N
  int*   perm = off + (M + N);                              // 2E (8 MB)
  unsigned* temp = (unsigned*)(perm + 2 * (size_t)E);       // 2E u32 (8 MB)
  int*   G    = (int*)(temp + 2 * (size_t)E);               // BK*NCH (575 KB)
  int*   rowTot = G + (size_t)BK * NCH;                     // BK
  int*   bucketBase = rowTot + BK;                          // BK+1
  int*   done = bucketBase + BK + 1;                        // 1

  int total4 = N * DIN / 4;
  k_p1<<<NCH + XB, 512, 0, stream>>>(vertex, edges, G, X, Xb, done,
                                     E, BKE, BK, NCH, total4);
  k_p1b<<<BK, 256, 0, stream>>>(G, rowTot, bucketBase, done, NCH, BK);
  p2_scatter<<<NCH, 512, 0, stream>>>(vertex, edges, G, bucketBase, temp,
                                      E, BKE, BK, NCH);
  p3_sort<<<BK, 256, 0, stream>>>(temp, bucketBase, off, perm, BKE, M, N);

  int edgeBlocks = (M + 31) / 32;        // 8 edges/wave, 4 waves/block
  k_edge<<<edgeBlocks, 256, 0, stream>>>(Xb, off, perm, dege, Xe, M);

  int nodeBlocks = (N + 63) / 64;        // 16 nodes/wave, 4 waves/block
  k_nodefin<<<nodeBlocks, 256, 0, stream>>>(Xe, off, perm, degv, W, b,
                                            out, N, M);
}

// Round 17
// 128.668 us; speedup vs baseline: 1.0270x; 1.0270x over previous
//
#include <hip/hip_runtime.h>

// UniGCNConv2: bucketed counting sort (packed keys, no global atomics) ->
// X cast bf16 (fused into p1) -> gather segment-mean Xe (bf16 store, f32
// accum, 8 edges/wave) -> gather+degv+L2norm xn (bf16, 8 nodes/wave, uint4
// loads, 2-register index prefetch) -> MFMA bf16 linear. 7 launches.
// r17: revert r16 fusion (LDS-conflict + occupancy regression); p3 at 512 thr.
// N=100000, M=200000, E=1e6, D_IN=64, out 128.

#define DIN 64
#define DOUT 128
#define CH 4096
#define BSHIFT 9          // fine range 512
#define FINE 512
#define PAYBITS 18
#define PAYMASK ((1u << PAYBITS) - 1u)
#define XB 256            // xcast helper blocks fused into p1
#define STAGE 8192        // p3 LDS pair-staging capacity

typedef float f32x4 __attribute__((ext_vector_type(4)));
typedef short bf16x8 __attribute__((ext_vector_type(8)));

__device__ __forceinline__ unsigned short f2b(float f) {
  unsigned u = __float_as_uint(f);
  u = u + 0x7fffu + ((u >> 16) & 1u);   // RNE
  return (unsigned short)(u >> 16);
}
__device__ __forceinline__ float b2f(unsigned s) {
  return __uint_as_float(s << 16);
}

// ---- P1 (512 thr): blocks [0,NCH): coarse hist (int4 reads);
// [NCH,NCH+XB): X->bf16. Block 0 zeroes the done counter.
__global__ __launch_bounds__(512) void k_p1(
    const int* __restrict__ vertex, const int* __restrict__ edges,
    int* __restrict__ G, const float* __restrict__ X,
    unsigned short* __restrict__ Xb, int* __restrict__ done,
    int E, int BKE, int BK, int NCH, int total4) {
  if (blockIdx.x == 0 && threadIdx.x == 0) *done = 0;
  if (blockIdx.x >= (unsigned)NCH) {  // xcast role
    int xb = blockIdx.x - NCH;
    for (int i = xb * 512 + threadIdx.x; i < total4; i += XB * 512) {
      float4 a = ((const float4*)X)[i];
      ushort4 r;
      r.x = f2b(a.x); r.y = f2b(a.y); r.z = f2b(a.z); r.w = f2b(a.w);
      ((ushort4*)Xb)[i] = r;
    }
    return;
  }
  __shared__ int h[1024];
  for (int i = threadIdx.x; i < BK; i += 512) h[i] = 0;
  __syncthreads();
  int c = blockIdx.x;
  int s = c * CH, e_ = min(E, s + CH);
  int n4 = (e_ - s) >> 2;
  const int4* ep = (const int4*)(edges + s);
  const int4* vp = (const int4*)(vertex + s);
  for (int i = threadIdx.x; i < n4; i += 512) {
    int4 ee = ep[i], vv = vp[i];
    atomicAdd(&h[ee.x >> BSHIFT], 1); atomicAdd(&h[ee.y >> BSHIFT], 1);
    atomicAdd(&h[ee.z >> BSHIFT], 1); atomicAdd(&h[ee.w >> BSHIFT], 1);
    atomicAdd(&h[BKE + (vv.x >> BSHIFT)], 1); atomicAdd(&h[BKE + (vv.y >> BSHIFT)], 1);
    atomicAdd(&h[BKE + (vv.z >> BSHIFT)], 1); atomicAdd(&h[BKE + (vv.w >> BSHIFT)], 1);
  }
  for (int i = s + (n4 << 2) + threadIdx.x; i < e_; i += 512) {
    atomicAdd(&h[edges[i] >> BSHIFT], 1);
    atomicAdd(&h[BKE + (vertex[i] >> BSHIFT)], 1);
  }
  __syncthreads();
  for (int b = threadIdx.x; b < BK; b += 512) G[(size_t)b * NCH + c] = h[b];
}

// ---- P1b: per-bucket row scan across chunks; last block scans bucket totals.
__global__ __launch_bounds__(256) void k_p1b(
    int* __restrict__ G, int* __restrict__ rowTot, int* __restrict__ bucketBase,
    int* __restrict__ done, int NCH, int BK) {
  int b = blockIdx.x;
  int* row = G + (size_t)b * NCH;
  __shared__ int wsum[4];
  __shared__ int carry;
  __shared__ bool amLast;
  if (threadIdx.x == 0) carry = 0;
  __syncthreads();
  for (int base = 0; base < NCH; base += 256) {
    int i = base + threadIdx.x;
    int v = (i < NCH) ? row[i] : 0;
    int lane = threadIdx.x & 63, wid = threadIdx.x >> 6;
    int inc = v;
    #pragma unroll
    for (int o = 1; o < 64; o <<= 1) {
      int t = __shfl_up(inc, o);
      if (lane >= o) inc += t;
    }
    if (lane == 63) wsum[wid] = inc;
    __syncthreads();
    int woff = carry;
    for (int w = 0; w < wid; ++w) woff += wsum[w];
    int excl = woff + inc - v;
    if (i < NCH) row[i] = excl;
    __syncthreads();
    if (threadIdx.x == 0) carry += wsum[0] + wsum[1] + wsum[2] + wsum[3];
    __syncthreads();
  }
  if (threadIdx.x == 0) {
    rowTot[b] = carry;
    __threadfence();
    amLast = (atomicAdd(done, 1) == gridDim.x - 1);
  }
  __syncthreads();
  if (!amLast) return;

  if (threadIdx.x == 0) carry = 0;
  __syncthreads();
  for (int base = 0; base < BK; base += 256) {
    int i = base + threadIdx.x;
    int v = (i < BK) ? atomicAdd(&rowTot[i], 0) : 0;  // device-fresh read
    int lane = threadIdx.x & 63, wid = threadIdx.x >> 6;
    int inc = v;
    #pragma unroll
    for (int o = 1; o < 64; o <<= 1) {
      int t = __shfl_up(inc, o);
      if (lane >= o) inc += t;
    }
    if (lane == 63) wsum[wid] = inc;
    __syncthreads();
    int woff = carry;
    for (int w = 0; w < wid; ++w) woff += wsum[w];
    int excl = woff + inc - v;
    if (i < BK) bucketBase[i] = excl;
    __syncthreads();
    if (threadIdx.x == 0) carry += wsum[0] + wsum[1] + wsum[2] + wsum[3];
    __syncthreads();
  }
  if (threadIdx.x == 0) bucketBase[BK] = carry;
}

// ---- P2 (512 thr): scatter packed (fine,payload) via LDS cursors; int4 reads.
__global__ __launch_bounds__(512) void p2_scatter(
    const int* __restrict__ vertex, const int* __restrict__ edges,
    const int* __restrict__ G, const int* __restrict__ bucketBase,
    unsigned* __restrict__ temp, int E, int BKE, int BK, int NCH) {
  __shared__ int curs[1024];
  int c = blockIdx.x;
  for (int b = threadIdx.x; b < BK; b += 512)
    curs[b] = bucketBase[b] + G[(size_t)b * NCH + c];
  __syncthreads();
  int s = c * CH, e_ = min(E, s + CH);
  int n4 = (e_ - s) >> 2;
  const int4* ep = (const int4*)(edges + s);
  const int4* vp = (const int4*)(vertex + s);
  for (int i = threadIdx.x; i < n4; i += 512) {
    int4 ee = ep[i], vv = vp[i];
    int p;
    p = atomicAdd(&curs[ee.x >> BSHIFT], 1);
    temp[p] = ((unsigned)(ee.x & (FINE - 1)) << PAYBITS) | (unsigned)vv.x;
    p = atomicAdd(&curs[BKE + (vv.x >> BSHIFT)], 1);
    temp[p] = ((unsigned)(vv.x & (FINE - 1)) << PAYBITS) | (unsigned)ee.x;
    p = atomicAdd(&curs[ee.y >> BSHIFT], 1);
    temp[p] = ((unsigned)(ee.y & (FINE - 1)) << PAYBITS) | (unsigned)vv.y;
    p = atomicAdd(&curs[BKE + (vv.y >> BSHIFT)], 1);
    temp[p] = ((unsigned)(vv.y & (FINE - 1)) << PAYBITS) | (unsigned)ee.y;
    p = atomicAdd(&curs[ee.z >> BSHIFT], 1);
    temp[p] = ((unsigned)(ee.z & (FINE - 1)) << PAYBITS) | (unsigned)vv.z;
    p = atomicAdd(&curs[BKE + (vv.z >> BSHIFT)], 1);
    temp[p] = ((unsigned)(vv.z & (FINE - 1)) << PAYBITS) | (unsigned)ee.z;
    p = atomicAdd(&curs[ee.w >> BSHIFT], 1);
    temp[p] = ((unsigned)(ee.w & (FINE - 1)) << PAYBITS) | (unsigned)vv.w;
    p = atomicAdd(&curs[BKE + (vv.w >> BSHIFT)], 1);
    temp[p] = ((unsigned)(vv.w & (FINE - 1)) << PAYBITS) | (unsigned)ee.w;
  }
  for (int i = s + (n4 << 2) + threadIdx.x; i < e_; i += 512) {
    int e = edges[i], v = vertex[i];
    int pE = atomicAdd(&curs[e >> BSHIFT], 1);
    temp[pE] = ((unsigned)(e & (FINE - 1)) << PAYBITS) | (unsigned)v;
    int pV = atomicAdd(&curs[BKE + (v >> BSHIFT)], 1);
    temp[pV] = ((unsigned)(v & (FINE - 1)) << PAYBITS) | (unsigned)e;
  }
}

// ---- P3 (512 thr): per-bucket fine counting sort -> off (inclusive ends)
// + perm. Pairs staged in LDS; one fine bin per thread for the scan.
__global__ __launch_bounds__(512) void p3_sort(
    const unsigned* __restrict__ temp, const int* __restrict__ bucketBase,
    int* __restrict__ off, int* __restrict__ perm, int BKE, int M, int N) {
  __shared__ int hist[FINE];
  __shared__ int pos[FINE];
  __shared__ int wsum[8];
  __shared__ unsigned pairsS[STAGE];
  int g = blockIdx.x;
  bool isE = g < BKE;
  int gg = isE ? g : g - BKE;
  int keyBase = gg << BSHIFT;
  int cap = isE ? M : N;
  int offBase = (isE ? 0 : M) + keyBase;
  int fineCount = min(FINE, cap - keyBase);
  int pairBase = bucketBase[g], pairEnd = bucketBase[g + 1];
  int cnt = pairEnd - pairBase;
  bool staged = cnt <= STAGE;

  hist[threadIdx.x] = 0;           // FINE == blockDim == 512
  __syncthreads();
  if (staged) {
    for (int i = threadIdx.x; i < cnt; i += 512) {
      unsigned p = temp[pairBase + i];
      pairsS[i] = p;
      atomicAdd(&hist[p >> PAYBITS], 1);
    }
  } else {
    for (int i = threadIdx.x; i < cnt; i += 512)
      atomicAdd(&hist[temp[pairBase + i] >> PAYBITS], 1);
  }
  __syncthreads();

  // block exclusive scan, one bin per thread (512 threads, 8 waves)
  int v = hist[threadIdx.x];
  int lane = threadIdx.x & 63, wid = threadIdx.x >> 6;
  int inc = v;
  #pragma unroll
  for (int o = 1; o < 64; o <<= 1) {
    int t = __shfl_up(inc, o);
    if (lane >= o) inc += t;
  }
  if (lane == 63) wsum[wid] = inc;
  __syncthreads();
  int woff = 0;
  for (int w = 0; w < wid; ++w) woff += wsum[w];
  int excl = woff + inc - v;
  pos[threadIdx.x] = excl;
  __syncthreads();

  if ((int)threadIdx.x < fineCount)
    off[offBase + threadIdx.x] = pairBase + pos[threadIdx.x] + hist[threadIdx.x];
  pos[threadIdx.x] += pairBase;    // same thread owns same bin: no race
  __syncthreads();

  if (staged) {
    for (int i = threadIdx.x; i < cnt; i += 512) {
      unsigned p = pairsS[i];
      int q = atomicAdd(&pos[p >> PAYBITS], 1);
      perm[q] = (int)(p & PAYMASK);
    }
  } else {
    for (int i = threadIdx.x; i < cnt; i += 512) {
      unsigned p = temp[pairBase + i];
      int q = atomicAdd(&pos[p >> PAYBITS], 1);
      perm[q] = (int)(p & PAYMASK);
    }
  }
}

// ---- compute passes ----

// 8 hyperedges per wave, one per 8-lane group; 8 lanes × uint4 = 128B row.
__global__ __launch_bounds__(256) void k_edge(
    const unsigned short* __restrict__ Xb, const int* __restrict__ off,
    const int* __restrict__ perm, const float* __restrict__ dege,
    unsigned short* __restrict__ Xe, int M) {
  long long gid = (long long)blockIdx.x * 256 + threadIdx.x;
  int wv = (int)(gid >> 6);
  int lane = threadIdx.x & 63;
  int g = lane >> 3, li = lane & 7;     // 8 groups of 8 lanes
  int e = wv * 8 + g;
  bool valid = e < M;
  int start = 0, end = 0;
  if (valid) { start = e ? off[e - 1] : 0; end = off[e]; }
  int deg = end - start;
  int myidx = (valid && li < deg) ? perm[start + li] : 0;
  int jmax = min(deg, 8);
  int jw = jmax;
  jw = max(jw, __shfl_xor(jw, 8));
  jw = max(jw, __shfl_xor(jw, 16));
  jw = max(jw, __shfl_xor(jw, 32));
  const uint4* X4 = (const uint4*)Xb;   // 8 uint4 per 64-elem row
  float acc[8] = {0.f, 0.f, 0.f, 0.f, 0.f, 0.f, 0.f, 0.f};
  #pragma unroll 4
  for (int j = 0; j < jw; ++j) {
    int v0 = __shfl(myidx, (g << 3) + j);   // all 64 lanes active
    if (j < jmax) {
      uint4 a = X4[(size_t)v0 * 8 + li];
      acc[0] += b2f(a.x & 0xffffu); acc[1] += b2f(a.x >> 16);
      acc[2] += b2f(a.y & 0xffffu); acc[3] += b2f(a.y >> 16);
      acc[4] += b2f(a.z & 0xffffu); acc[5] += b2f(a.z >> 16);
      acc[6] += b2f(a.w & 0xffffu); acc[7] += b2f(a.w >> 16);
    }
  }
  for (int j = 8; j < deg; ++j) {           // tail (deg>8)
    int v0 = perm[start + j];
    uint4 a = X4[(size_t)v0 * 8 + li];
    acc[0] += b2f(a.x & 0xffffu); acc[1] += b2f(a.x >> 16);
    acc[2] += b2f(a.y & 0xffffu); acc[3] += b2f(a.y >> 16);
    acc[4] += b2f(a.z & 0xffffu); acc[5] += b2f(a.z >> 16);
    acc[6] += b2f(a.w & 0xffffu); acc[7] += b2f(a.w >> 16);
  }
  if (valid) {
    float s = dege[e] / fmaxf((float)deg, 1.0f);
    uint4 r;
    r.x = (unsigned)f2b(acc[0] * s) | ((unsigned)f2b(acc[1] * s) << 16);
    r.y = (unsigned)f2b(acc[2] * s) | ((unsigned)f2b(acc[3] * s) << 16);
    r.z = (unsigned)f2b(acc[4] * s) | ((unsigned)f2b(acc[5] * s) << 16);
    r.w = (unsigned)f2b(acc[6] * s) | ((unsigned)f2b(acc[7] * s) << 16);
    ((uint4*)Xe)[(size_t)e * 8 + li] = r;
  }
}

// Node aggregate: 8 nodes/wave, one per 8-lane group; 8 lanes × uint4 row
// loads; 2-register index prefetch (my0 for j<8, my1 for j in [8,16)).
__global__ __launch_bounds__(256) void k_nodeagg(
    const unsigned short* __restrict__ Xe, const int* __restrict__ off,
    const int* __restrict__ perm, const float* __restrict__ degv,
    unsigned short* __restrict__ xn, int N, int M) {
  long long gid = (long long)blockIdx.x * 256 + threadIdx.x;
  int wv = (int)(gid >> 6);
  int lane = threadIdx.x & 63;
  int g = lane >> 3, li = lane & 7;     // 8 groups of 8 lanes
  int node = wv * 8 + g;
  bool valid = node < N;
  int start = 0, end = 0;
  if (valid) { start = off[M + node - 1]; end = off[M + node]; }  // node0: off[M-1]==E
  int deg = end - start;
  int my0 = (valid && li < deg) ? perm[start + li] : 0;
  int my1 = (valid && 8 + li < deg) ? perm[start + 8 + li] : 0;
  int jmax0 = min(deg, 8);
  int jmax1 = min(max(deg - 8, 0), 8);
  int jw0 = jmax0, jw1 = jmax1;
  jw0 = max(jw0, __shfl_xor(jw0, 8)); jw1 = max(jw1, __shfl_xor(jw1, 8));
  jw0 = max(jw0, __shfl_xor(jw0, 16)); jw1 = max(jw1, __shfl_xor(jw1, 16));
  jw0 = max(jw0, __shfl_xor(jw0, 32)); jw1 = max(jw1, __shfl_xor(jw1, 32));
  const uint4* Xe4 = (const uint4*)Xe;  // 8 uint4 per 64-elem row
  float acc[8] = {0.f, 0.f, 0.f, 0.f, 0.f, 0.f, 0.f, 0.f};
  #pragma unroll 4
  for (int j = 0; j < jw0; ++j) {
    int e0 = __shfl(my0, (g << 3) + j);   // all 64 lanes active
    if (j < jmax0) {
      uint4 a = Xe4[(size_t)e0 * 8 + li];
      acc[0] += b2f(a.x & 0xffffu); acc[1] += b2f(a.x >> 16);
      acc[2] += b2f(a.y & 0xffffu); acc[3] += b2f(a.y >> 16);
      acc[4] += b2f(a.z & 0xffffu); acc[5] += b2f(a.z >> 16);
      acc[6] += b2f(a.w & 0xffffu); acc[7] += b2f(a.w >> 16);
    }
  }
  #pragma unroll 4
  for (int j = 0; j < jw1; ++j) {
    int e0 = __shfl(my1, (g << 3) + j);   // all 64 lanes active
    if (j < jmax1) {
      uint4 a = Xe4[(size_t)e0 * 8 + li];
      acc[0] += b2f(a.x & 0xffffu); acc[1] += b2f(a.x >> 16);
      acc[2] += b2f(a.y & 0xffffu); acc[3] += b2f(a.y >> 16);
      acc[4] += b2f(a.z & 0xffffu); acc[5] += b2f(a.z >> 16);
      acc[6] += b2f(a.w & 0xffffu); acc[7] += b2f(a.w >> 16);
    }
  }
  for (int j = 16; j < deg; ++j) {        // tail (deg>16), ~2% of nodes
    int e0 = perm[start + j];
    uint4 a = Xe4[(size_t)e0 * 8 + li];
    acc[0] += b2f(a.x & 0xffffu); acc[1] += b2f(a.x >> 16);
    acc[2] += b2f(a.y & 0xffffu); acc[3] += b2f(a.y >> 16);
    acc[4] += b2f(a.z & 0xffffu); acc[5] += b2f(a.z >> 16);
    acc[6] += b2f(a.w & 0xffffu); acc[7] += b2f(a.w >> 16);
  }
  float dv = valid ? degv[node] : 0.f;
  float ss = 0.f;
  #pragma unroll
  for (int i = 0; i < 8; ++i) { acc[i] *= dv; ss += acc[i] * acc[i]; }
  #pragma unroll
  for (int o = 1; o <= 4; o <<= 1) ss += __shfl_xor(ss, o);  // within group
  float sc = ss > 0.0f ? 1.0f / sqrtf(ss) : 0.0f;
  if (valid) {
    uint4 r;
    r.x = (unsigned)f2b(acc[0] * sc) | ((unsigned)f2b(acc[1] * sc) << 16);
    r.y = (unsigned)f2b(acc[2] * sc) | ((unsigned)f2b(acc[3] * sc) << 16);
    r.z = (unsigned)f2b(acc[4] * sc) | ((unsigned)f2b(acc[5] * sc) << 16);
    r.w = (unsigned)f2b(acc[6] * sc) | ((unsigned)f2b(acc[7] * sc) << 16);
    ((uint4*)xn)[(size_t)node * 8 + li] = r;
  }
}

// out[N x 128] = xn(bf16) @ W + b via mfma_f32_16x16x32_bf16.
// A frag: row = lane&15, k = (lane>>4)*8 + j. B frag: col = lane&15, same k.
// C/D: col = lane&15, row = (lane>>4)*4 + reg  [m89-verified].
#define WPAD 72
__global__ __launch_bounds__(256) void k_linear(
    const unsigned short* __restrict__ xn, const float* __restrict__ W,
    const float* __restrict__ bias, float* __restrict__ out, int N) {
  __shared__ unsigned short Wt[DOUT * WPAD];
  for (int i = threadIdx.x; i < DIN * DOUT; i += 256) {
    int k = i >> 7, c = i & 127;   // W[k][c]
    Wt[c * WPAD + k] = f2b(W[i]);
  }
  __syncthreads();
  int lane = threadIdx.x & 63;
  int wid = threadIdx.x >> 6;
  int r = lane & 15, h = lane >> 4;

  bf16x8 Bf[8][2];
  #pragma unroll
  for (int c = 0; c < 8; ++c) {
    #pragma unroll
    for (int ks = 0; ks < 2; ++ks) {
      int col = c * 16 + r;
      int k0 = ks * 32 + h * 8;
      Bf[c][ks] = *(const bf16x8*)&Wt[col * WPAD + k0];
    }
  }
  float bcol[8];
  #pragma unroll
  for (int c = 0; c < 8; ++c) bcol[c] = bias[c * 16 + r];

  int strips = (N + 15) >> 4;
  for (int s = blockIdx.x * 4 + wid; s < strips; s += gridDim.x * 4) {
    int row0 = s << 4;
    const unsigned short* xrow = xn + (size_t)(row0 + r) * DIN;
    bf16x8 a0 = *(const bf16x8*)&xrow[h * 8];
    bf16x8 a1 = *(const bf16x8*)&xrow[32 + h * 8];
    #pragma unroll
    for (int c = 0; c < 8; ++c) {
      f32x4 acc = {bcol[c], bcol[c], bcol[c], bcol[c]};
      acc = __builtin_amdgcn_mfma_f32_16x16x32_bf16(a0, Bf[c][0], acc, 0, 0, 0);
      acc = __builtin_amdgcn_mfma_f32_16x16x32_bf16(a1, Bf[c][1], acc, 0, 0, 0);
      #pragma unroll
      for (int q = 0; q < 4; ++q)
        out[(size_t)(row0 + h * 4 + q) * DOUT + c * 16 + r] = acc[q];
    }
  }
}

extern "C" void kernel_launch(void* const* d_in, const int* in_sizes, int n_in,
                              void* d_out, int out_size, void* d_ws, size_t ws_size,
                              hipStream_t stream) {
  const float* X      = (const float*)d_in[0];
  const int*   vertex = (const int*)d_in[1];
  const int*   edges  = (const int*)d_in[2];
  const float* dege   = (const float*)d_in[3];
  const float* degv   = (const float*)d_in[4];
  const float* W      = (const float*)d_in[5];
  const float* b      = (const float*)d_in[6];
  float* out = (float*)d_out;

  int N = in_sizes[0] / DIN;   // 100000
  int E = in_sizes[1];         // 1000000
  int M = in_sizes[3];         // 200000

  int NCH = (E + CH - 1) / CH;                 // 245
  int BKE = (M + FINE - 1) >> BSHIFT;          // 391
  int BKV = (N + FINE - 1) >> BSHIFT;          // 196
  int BK  = BKE + BKV;                         // 587

  // workspace layout; temp (dead after p3) aliases xn (written after p3)
  unsigned short* Xe = (unsigned short*)d_ws;               // M*64 bf16 (25.6 MB)
  unsigned short* Xb = Xe + (size_t)M * DIN;                // N*64 bf16 (12.8 MB)
  int*   off  = (int*)(Xb + (size_t)N * DIN);               // M+N
  int*   perm = off + (M + N);                              // 2E (8 MB)
  char*  R    = (char*)(perm + 2 * (size_t)E);
  unsigned*       temp = (unsigned*)R;                      // 2E u32 (8 MB)
  unsigned short* xn   = (unsigned short*)R;                // N*64 bf16 (12.8 MB)
  size_t rBytes = (size_t)2 * E * 4;
  size_t xBytes = (size_t)N * DIN * 2;
  char*  R2   = R + (rBytes > xBytes ? rBytes : xBytes);
  int*   G    = (int*)R2;                                   // BK*NCH (575 KB)
  int*   rowTot = G + (size_t)BK * NCH;                     // BK
  int*   bucketBase = rowTot + BK;                          // BK+1
  int*   done = bucketBase + BK + 1;                        // 1

  int total4 = N * DIN / 4;
  k_p1<<<NCH + XB, 512, 0, stream>>>(vertex, edges, G, X, Xb, done,
                                     E, BKE, BK, NCH, total4);
  k_p1b<<<BK, 256, 0, stream>>>(G, rowTot, bucketBase, done, NCH, BK);
  p2_scatter<<<NCH, 512, 0, stream>>>(vertex, edges, G, bucketBase, temp,
                                      E, BKE, BK, NCH);
  p3_sort<<<BK, 512, 0, stream>>>(temp, bucketBase, off, perm, BKE, M, N);

  int edgeBlocks = (M + 31) / 32;        // 8 edges/wave, 4 waves/block
  k_edge<<<edgeBlocks, 256, 0, stream>>>(Xb, off, perm, dege, Xe, M);

  int nodeWaves = (N + 7) / 8;           // 8 nodes/wave
  int nodeBlocks = (nodeWaves + 3) / 4;
  k_nodeagg<<<nodeBlocks, 256, 0, stream>>>(Xe, off, perm, degv, xn, N, M);

  int strips = (N + 15) >> 4;
  int linBlocks = (strips + 3) / 4;      // one strip per wave
  k_linear<<<linBlocks, 256, 0, stream>>>(xn, W, b, out, N);
}